// Round 5
// baseline (315.640 us; speedup 1.0000x reference)
//
#include <hip/hip_runtime.h>
#include <hip/hip_bf16.h>

#define BB 8
#define LL 200
#define HH 128
#define NHEAD 4
#define HDIM 32
#define NBLK 2
#define BL (BB * LL)
#define NT 257            // TIME_SPAN+1
#define QT 16             // queries per attention tile
#define SP 208            // S tile stride (>= max k index + 1)
#define KSP 36            // staging row stride (pad for banks, 16B aligned)
#define NQT 13            // ceil(200/16)

static constexpr float SQRT_H    = 11.313708498984761f;   // sqrt(128)
static constexpr float INV_SCALE = 0.17677669529663687f;  // 1/sqrt(32)
static constexpr float PADV      = -4294967295.0f;        // -2^32+1

// ---- fused [embed]+LN+QKV, 4 rows/block, 256 threads ----------------------
// Q = (LN(x)@Wq^T+bq)*INV_SCALE ; K = x@Wk^T+bk+posK ; V = x@Wv^T+bv+posV
__global__ void k_lnqkv(const float* __restrict__ seqs_in,
                        const int* __restrict__ log_seqs,
                        const float* __restrict__ item_emb,
                        const float* __restrict__ g, const float* __restrict__ bia,
                        const float* __restrict__ Wq, const float* __restrict__ bq,
                        const float* __restrict__ Wk, const float* __restrict__ bk,
                        const float* __restrict__ Wv, const float* __restrict__ bv,
                        const float* __restrict__ posK, const float* __restrict__ posV,
                        float* __restrict__ Qin, float* __restrict__ Q,
                        float* __restrict__ K, float* __restrict__ V) {
    int row0 = blockIdx.x * 4;             // 200 % 4 == 0: no batch straddle
    int tid = threadIdx.x;
    int wv = tid >> 6, ln = tid & 63;
    __shared__ float xs[4][HH], xq[4][HH];

    {   // wave wv owns row wv: load + LN (2 elems/lane, 64-lane reduce)
        int row = row0 + wv;
        float v0, v1;
        if (seqs_in) {
            v0 = seqs_in[(size_t)row * HH + ln];
            v1 = seqs_in[(size_t)row * HH + ln + 64];
        } else {
            int idx = log_seqs[row];
            if (idx == 0) { v0 = 0.f; v1 = 0.f; }
            else {
                v0 = item_emb[(size_t)idx * HH + ln] * SQRT_H;
                v1 = item_emb[(size_t)idx * HH + ln + 64] * SQRT_H;
            }
        }
        xs[wv][ln] = v0; xs[wv][ln + 64] = v1;
        float s = v0 + v1, s2 = v0 * v0 + v1 * v1;
        for (int off = 32; off; off >>= 1) {
            s  += __shfl_xor(s, off);
            s2 += __shfl_xor(s2, off);
        }
        float mean = s * (1.f / HH);
        float var  = s2 * (1.f / HH) - mean * mean;
        float inv  = 1.f / sqrtf(var + 1e-8f);
        float q0 = (v0 - mean) * inv * g[ln]      + bia[ln];
        float q1 = (v1 - mean) * inv * g[ln + 64] + bia[ln + 64];
        xq[wv][ln] = q0; xq[wv][ln + 64] = q1;
        Qin[(size_t)row * HH + ln]      = q0;
        Qin[(size_t)row * HH + ln + 64] = q1;
    }
    __syncthreads();

    int j  = tid & 127;      // output column
    int rh = tid >> 7;       // 0/1 -> rows rh*2, rh*2+1
    const float4* wq4 = (const float4*)(Wq + (size_t)j * HH);
    const float4* wk4 = (const float4*)(Wk + (size_t)j * HH);
    const float4* wv4 = (const float4*)(Wv + (size_t)j * HH);
    float aq[2] = {0,0}, ak[2] = {0,0}, av[2] = {0,0};
    for (int i = 0; i < HH / 4; i++) {
        float4 wq = wq4[i], wk = wk4[i], wvv = wv4[i];
        #pragma unroll
        for (int r = 0; r < 2; r++) {
            float4 a = *(const float4*)&xq[rh * 2 + r][i * 4];
            float4 x = *(const float4*)&xs[rh * 2 + r][i * 4];
            aq[r] += a.x * wq.x + a.y * wq.y + a.z * wq.z + a.w * wq.w;
            ak[r] += x.x * wk.x + x.y * wk.y + x.z * wk.z + x.w * wk.w;
            av[r] += x.x * wvv.x + x.y * wvv.y + x.z * wvv.z + x.w * wvv.w;
        }
    }
    #pragma unroll
    for (int r = 0; r < 2; r++) {
        int row = row0 + rh * 2 + r;
        int l = row % LL;
        Q[(size_t)row * HH + j] = (aq[r] + bq[j]) * INV_SCALE;
        K[(size_t)row * HH + j] = ak[r] + bk[j] + posK[l * HH + j];
        V[(size_t)row * HH + j] = av[r] + bv[j] + posV[l * HH + j];
    }
}

// ---- tiled attention: one block per (b, head, 16-q tile), 256 threads -----
// DT[qi][tau] = Qh[q0+qi] . timeKh[tau]          (GEMM, LDS-staged)
// S [qi][k]   = Qh . Kh[k] + DT[qi][tm[q][k]]    (GEMM + LDS gather, causal)
// P = softmax(S) ; W[qi][tau] = sum_{tm=tau} p   (LDS scatter)
// O [qi][d]   = P@Vh + W@timeVh                  (coalesced global reads)
__global__ void k_attn(const float* __restrict__ Q, const float* __restrict__ K,
                       const float* __restrict__ V,
                       const float* __restrict__ timeK, const float* __restrict__ timeV,
                       const int* __restrict__ tm,
                       float* __restrict__ att) {
    int bn = blockIdx.x & 31;
    int b = bn >> 2, n = bn & 3;
    int qt = (NQT - 1) - (blockIdx.x >> 5);   // heavy (high-q) tiles first
    int q0 = qt * QT;
    int tid = threadIdx.x;
    int wv = tid >> 6, ln = tid & 63;

    __shared__ float Qs[QT * KSP];        // Q tile          2.3 KB
    __shared__ float Kst[64 * KSP];       // staging         9.2 KB
    __shared__ float DTW[QT * NT];        // DT, then W     16.4 KB
    __shared__ float S[QT * SP];          // scores -> P    13.3 KB
    __shared__ int   tmst[QT * LL];       // tm tile        12.8 KB

    // ---- A: load Q tile (zero-fill q>=200) + tm tile ----
    if (tid < 128) {
        int qi = tid >> 3, d4 = tid & 7;
        int q = q0 + qi;
        float4 v = make_float4(0.f, 0.f, 0.f, 0.f);
        if (q < LL) v = *(const float4*)(Q + ((size_t)(b * LL + q)) * HH + n * HDIM + d4 * 4);
        *(float4*)(Qs + qi * KSP + d4 * 4) = v;
    }
    for (int qi = 0; qi < QT; qi++) {
        int q = q0 + qi;
        if (q < LL && tid < LL)
            tmst[qi * LL + tid] = tm[((size_t)(b * LL + q)) * LL + tid];
    }
    __syncthreads();

    // ---- B: DT tile = Qs @ timeKh^T ----
    for (int c = 0; c < 5; c++) {
        for (int j = tid; j < 64 * 8; j += 256) {
            int r = j >> 3, d4 = j & 7;
            int tau = c * 64 + r;
            float4 v = make_float4(0.f, 0.f, 0.f, 0.f);
            if (tau < NT) v = *(const float4*)(timeK + (size_t)tau * HH + n * HDIM + d4 * 4);
            *(float4*)(Kst + r * KSP + d4 * 4) = v;
        }
        __syncthreads();
        float acc[4] = {0, 0, 0, 0};
        for (int d4 = 0; d4 < 8; d4++) {
            float4 kv = *(const float4*)(Kst + ln * KSP + d4 * 4);
            #pragma unroll
            for (int r = 0; r < 4; r++) {
                float4 qv = *(const float4*)(Qs + (wv * 4 + r) * KSP + d4 * 4);
                acc[r] += qv.x * kv.x + qv.y * kv.y + qv.z * kv.z + qv.w * kv.w;
            }
        }
        int tau = c * 64 + ln;
        if (tau < NT) {
            #pragma unroll
            for (int r = 0; r < 4; r++) DTW[(wv * 4 + r) * NT + tau] = acc[r];
        }
        __syncthreads();
    }

    // ---- C: S tile = Qs @ Kh^T + DT gather, causal mask ----
    int kmax = min(q0 + QT - 1, LL - 1);
    int nch = (kmax >> 6) + 1;
    for (int c = 0; c < nch; c++) {
        for (int j = tid; j < 64 * 8; j += 256) {
            int r = j >> 3, d4 = j & 7;
            int k = c * 64 + r;
            float4 v = make_float4(0.f, 0.f, 0.f, 0.f);
            if (k < LL) v = *(const float4*)(K + ((size_t)(b * LL + k)) * HH + n * HDIM + d4 * 4);
            *(float4*)(Kst + r * KSP + d4 * 4) = v;
        }
        __syncthreads();
        float acc[4] = {0, 0, 0, 0};
        for (int d4 = 0; d4 < 8; d4++) {
            float4 kv = *(const float4*)(Kst + ln * KSP + d4 * 4);
            #pragma unroll
            for (int r = 0; r < 4; r++) {
                float4 qv = *(const float4*)(Qs + (wv * 4 + r) * KSP + d4 * 4);
                acc[r] += qv.x * kv.x + qv.y * kv.y + qv.z * kv.z + qv.w * kv.w;
            }
        }
        int k = c * 64 + ln;
        if (k <= kmax) {
            #pragma unroll
            for (int r = 0; r < 4; r++) {
                int qi = wv * 4 + r, q = q0 + qi;
                float s = PADV;
                if (q < LL && k <= q)
                    s = acc[r] + DTW[qi * NT + tmst[qi * LL + k]];
                S[qi * SP + k] = s;
            }
        }
        __syncthreads();
    }

    // ---- D: softmax rows + scatter W (DTW reused as W) ----
    for (int j = tid; j < QT * NT; j += 256) DTW[j] = 0.f;
    __syncthreads();
    #pragma unroll
    for (int r = 0; r < 4; r++) {
        int qi = wv * 4 + r, q = q0 + qi;
        if (q >= LL) continue;
        float sr[4]; int cnt = 0;
        float m = -3.0e38f;
        for (int k = ln; k <= q; k += 64) { float s = S[qi * SP + k]; sr[cnt++] = s; m = fmaxf(m, s); }
        for (int off = 32; off; off >>= 1) m = fmaxf(m, __shfl_xor(m, off));
        float sum = 0.f;
        for (int j2 = 0; j2 < cnt; j2++) { float e = __expf(sr[j2] - m); sr[j2] = e; sum += e; }
        for (int off = 32; off; off >>= 1) sum += __shfl_xor(sum, off);
        float inv = 1.f / sum;
        int j2 = 0;
        for (int k = ln; k <= q; k += 64) {
            float p = sr[j2++] * inv;
            S[qi * SP + k] = p;
            atomicAdd(&DTW[qi * NT + tmst[qi * LL + k]], p);
        }
    }
    __syncthreads();

    // ---- E: O = P @ Vh + W @ timeVh (coalesced 128B row reads) ----
    int d = tid & 31, qg = tid >> 5;
    #pragma unroll
    for (int h2 = 0; h2 < 2; h2++) {
        int qi = qg + h2 * 8;
        int q = q0 + qi;
        if (q >= LL) continue;
        const float* vb  = V + ((size_t)(b * LL)) * HH + n * HDIM + d;
        const float* tvb = timeV + n * HDIM + d;
        const float* Pr = S + qi * SP;
        const float* Wr = DTW + qi * NT;
        float a0 = 0.f, a1 = 0.f, a2 = 0.f, a3 = 0.f;
        int k = 0;
        for (; k + 3 <= q; k += 4) {
            a0 += Pr[k]     * vb[(size_t)k * HH];
            a1 += Pr[k + 1] * vb[(size_t)(k + 1) * HH];
            a2 += Pr[k + 2] * vb[(size_t)(k + 2) * HH];
            a3 += Pr[k + 3] * vb[(size_t)(k + 3) * HH];
        }
        for (; k <= q; k++) a0 += Pr[k] * vb[(size_t)k * HH];
        for (int t = 0; t < 256; t += 4) {
            a0 += Wr[t]     * tvb[(size_t)t * HH];
            a1 += Wr[t + 1] * tvb[(size_t)(t + 1) * HH];
            a2 += Wr[t + 2] * tvb[(size_t)(t + 2) * HH];
            a3 += Wr[t + 3] * tvb[(size_t)(t + 3) * HH];
        }
        a0 += Wr[256] * tvb[(size_t)256 * HH];
        att[((size_t)(b * LL + q)) * HH + n * HDIM + d] = (a0 + a1) + (a2 + a3);
    }
}

// ---- fused LN + FF1 + FF2 + keep, 4 rows/block, 256 threads ---------------
__global__ void k_lnffn(const float* __restrict__ Qin, const float* __restrict__ att,
                        const float* __restrict__ g, const float* __restrict__ bia,
                        const float* __restrict__ W1, const float* __restrict__ b1,
                        const float* __restrict__ W2, const float* __restrict__ b2,
                        const int* __restrict__ log_seqs, float* __restrict__ out) {
    int row0 = blockIdx.x * 4;
    int tid = threadIdx.x;
    int wv = tid >> 6, ln = tid & 63;
    __shared__ float xr[4][HH], h1s[4][HH];

    {   // wave wv owns row wv
        int row = row0 + wv;
        float v0 = Qin[(size_t)row * HH + ln]      + att[(size_t)row * HH + ln];
        float v1 = Qin[(size_t)row * HH + ln + 64] + att[(size_t)row * HH + ln + 64];
        float s = v0 + v1, s2 = v0 * v0 + v1 * v1;
        for (int off = 32; off; off >>= 1) {
            s  += __shfl_xor(s, off);
            s2 += __shfl_xor(s2, off);
        }
        float mean = s * (1.f / HH);
        float var  = s2 * (1.f / HH) - mean * mean;
        float inv  = 1.f / sqrtf(var + 1e-8f);
        xr[wv][ln]      = (v0 - mean) * inv * g[ln]      + bia[ln];
        xr[wv][ln + 64] = (v1 - mean) * inv * g[ln + 64] + bia[ln + 64];
    }
    __syncthreads();

    int j  = tid & 127;
    int rh = tid >> 7;
    const float4* w1 = (const float4*)(W1 + (size_t)j * HH);
    float a[2] = {0, 0};
    for (int i = 0; i < HH / 4; i++) {
        float4 w = w1[i];
        #pragma unroll
        for (int r = 0; r < 2; r++) {
            float4 x = *(const float4*)&xr[rh * 2 + r][i * 4];
            a[r] += x.x * w.x + x.y * w.y + x.z * w.z + x.w * w.w;
        }
    }
    #pragma unroll
    for (int r = 0; r < 2; r++) {
        float t = a[r] + b1[j];
        h1s[rh * 2 + r][j] = t > 0.f ? t : 0.f;
    }
    __syncthreads();

    const float4* w2 = (const float4*)(W2 + (size_t)j * HH);
    float c[2] = {0, 0};
    for (int i = 0; i < HH / 4; i++) {
        float4 w = w2[i];
        #pragma unroll
        for (int r = 0; r < 2; r++) {
            float4 x = *(const float4*)&h1s[rh * 2 + r][i * 4];
            c[r] += x.x * w.x + x.y * w.y + x.z * w.z + x.w * w.w;
        }
    }
    #pragma unroll
    for (int r = 0; r < 2; r++) {
        int row = row0 + rh * 2 + r;
        float t = c[r] + b2[j] + xr[rh * 2 + r][j];
        out[(size_t)row * HH + j] = (log_seqs[row] == 0) ? 0.f : t;
    }
}

// ---- fused last-LN + pos/neg logits: one block per row --------------------
__global__ void k_lnlogits(const float* __restrict__ seqs,
                           const float* __restrict__ g, const float* __restrict__ bia,
                           const float* __restrict__ item_emb,
                           const int* __restrict__ pos, const int* __restrict__ neg,
                           float* __restrict__ out) {
    int row = blockIdx.x;
    int h = threadIdx.x;
    float v = seqs[(size_t)row * HH + h];
    float s = v, s2 = v * v;
    for (int off = 32; off; off >>= 1) {
        s  += __shfl_xor(s, off);
        s2 += __shfl_xor(s2, off);
    }
    __shared__ float r1[2], r2[2];
    if ((h & 63) == 0) { r1[h >> 6] = s; r2[h >> 6] = s2; }
    __syncthreads();
    float mean = (r1[0] + r1[1]) * (1.f / HH);
    float var  = (r2[0] + r2[1]) * (1.f / HH) - mean * mean;
    float inv = 1.f / sqrtf(var + 1e-8f);
    float f = (v - mean) * inv * g[h] + bia[h];

    int ip = pos[row], in_ = neg[row];
    float vp = f * item_emb[(size_t)ip * HH + h];
    float vn = f * item_emb[(size_t)in_ * HH + h];
    for (int off = 32; off; off >>= 1) {
        vp += __shfl_xor(vp, off);
        vn += __shfl_xor(vn, off);
    }
    __shared__ float rp[2], rn[2];
    if ((h & 63) == 0) { rp[h >> 6] = vp; rn[h >> 6] = vn; }
    __syncthreads();
    if (h == 0) {
        out[row]      = rp[0] + rp[1];
        out[BL + row] = rn[0] + rn[1];
    }
}

extern "C" void kernel_launch(void* const* d_in, const int* in_sizes, int n_in,
                              void* d_out, int out_size, void* d_ws, size_t ws_size,
                              hipStream_t stream) {
    const int* log_seqs   = (const int*)d_in[1];
    const int* tm         = (const int*)d_in[2];
    const int* pos_seqs   = (const int*)d_in[3];
    const int* neg_seqs   = (const int*)d_in[4];
    const float* item_emb = (const float*)d_in[5];
    const float* posK     = (const float*)d_in[6];
    const float* posV     = (const float*)d_in[7];
    const float* timeK    = (const float*)d_in[8];
    const float* timeV    = (const float*)d_in[9];
    const float* attn_g   = (const float*)d_in[10];
    const float* attn_b   = (const float*)d_in[11];
    const float* Wq       = (const float*)d_in[12];
    const float* bq       = (const float*)d_in[13];
    const float* Wk       = (const float*)d_in[14];
    const float* bk       = (const float*)d_in[15];
    const float* Wv       = (const float*)d_in[16];
    const float* bv       = (const float*)d_in[17];
    const float* fwd_g    = (const float*)d_in[18];
    const float* fwd_b    = (const float*)d_in[19];
    const float* W1       = (const float*)d_in[20];
    const float* b1       = (const float*)d_in[21];
    const float* W2       = (const float*)d_in[22];
    const float* b2       = (const float*)d_in[23];
    const float* last_g   = (const float*)d_in[24];
    const float* last_b   = (const float*)d_in[25];

    float* seqs = (float*)d_ws;            // 6 x B*L*H f32 = ~4.9 MB
    float* Qin  = seqs + (size_t)BL * HH;
    float* Qb   = Qin  + (size_t)BL * HH;
    float* Kb   = Qb   + (size_t)BL * HH;
    float* Vb   = Kb   + (size_t)BL * HH;
    float* att  = Vb   + (size_t)BL * HH;

    for (int i = 0; i < NBLK; i++) {
        k_lnqkv<<<BL / 4, 256, 0, stream>>>(i == 0 ? nullptr : seqs, log_seqs, item_emb,
                                            attn_g + i * HH, attn_b + i * HH,
                                            Wq + (size_t)i * HH * HH, bq + i * HH,
                                            Wk + (size_t)i * HH * HH, bk + i * HH,
                                            Wv + (size_t)i * HH * HH, bv + i * HH,
                                            posK, posV, Qin, Qb, Kb, Vb);
        k_attn<<<NQT * 32, 256, 0, stream>>>(Qb, Kb, Vb, timeK, timeV, tm, att);
        k_lnffn<<<BL / 4, 256, 0, stream>>>(Qin, att, fwd_g + i * HH, fwd_b + i * HH,
                                            W1 + (size_t)i * HH * HH, b1 + i * HH,
                                            W2 + (size_t)i * HH * HH, b2 + i * HH,
                                            log_seqs, seqs);
    }
    k_lnlogits<<<BL, HH, 0, stream>>>(seqs, last_g, last_b, item_emb,
                                      pos_seqs, neg_seqs, (float*)d_out);
}

// Round 6
// 269.934 us; speedup vs baseline: 1.1693x; 1.1693x over previous
//
#include <hip/hip_runtime.h>
#include <hip/hip_bf16.h>

#define BB 8
#define LL 200
#define HH 128
#define NHEAD 4
#define HDIM 32
#define NBLK 2
#define BL (BB * LL)
#define NT 257            // TIME_SPAN+1
#define QT 8              // queries per attention tile
#define NQT 25            // 200/8
#define SSP 208           // score row stride
#define KTP 66            // KstT row stride (floats)

static constexpr float SQRT_H    = 11.313708498984761f;   // sqrt(128)
static constexpr float INV_SCALE = 0.17677669529663687f;  // 1/sqrt(32)
static constexpr float PADV      = -4294967295.0f;        // -2^32+1

// ===== fused [embed]+LN+QKV: 4 rows/block, 128 threads, W LDS-staged ======
__global__ void k_lnqkv(const float* __restrict__ seqs_in,
                        const int* __restrict__ log_seqs,
                        const float* __restrict__ item_emb,
                        const float* __restrict__ g, const float* __restrict__ bia,
                        const float* __restrict__ Wq, const float* __restrict__ bq,
                        const float* __restrict__ Wk, const float* __restrict__ bk,
                        const float* __restrict__ Wv, const float* __restrict__ bv,
                        const float* __restrict__ posK, const float* __restrict__ posV,
                        float* __restrict__ Qin, float* __restrict__ Q,
                        float* __restrict__ K, float* __restrict__ V) {
    int row0 = blockIdx.x * 4;
    int tid = threadIdx.x;
    int wv = tid >> 6, ln = tid & 63;
    __shared__ float xT[HH][8];           // [feature][0-3: LN'd rows, 4-7: raw rows]
    __shared__ float Wst[3 * HH * 33];    // k-chunk of 32 per mat

    for (int rr = 0; rr < 2; rr++) {      // wave wv handles rows 2wv, 2wv+1
        int r = 2 * wv + rr;
        int row = row0 + r;
        float v0, v1;
        if (seqs_in) {
            v0 = seqs_in[(size_t)row * HH + ln];
            v1 = seqs_in[(size_t)row * HH + ln + 64];
        } else {
            int idx = log_seqs[row];
            if (idx == 0) { v0 = 0.f; v1 = 0.f; }
            else {
                v0 = item_emb[(size_t)idx * HH + ln] * SQRT_H;
                v1 = item_emb[(size_t)idx * HH + ln + 64] * SQRT_H;
            }
        }
        float s = v0 + v1, s2 = v0 * v0 + v1 * v1;
        for (int off = 32; off; off >>= 1) {
            s  += __shfl_xor(s, off);
            s2 += __shfl_xor(s2, off);
        }
        float mean = s * (1.f / HH);
        float var  = s2 * (1.f / HH) - mean * mean;
        float inv  = 1.f / sqrtf(var + 1e-8f);
        float q0v = (v0 - mean) * inv * g[ln]      + bia[ln];
        float q1v = (v1 - mean) * inv * g[ln + 64] + bia[ln + 64];
        xT[ln][r] = q0v;      xT[ln + 64][r] = q1v;
        xT[ln][4 + r] = v0;   xT[ln + 64][4 + r] = v1;
        Qin[(size_t)row * HH + ln]      = q0v;
        Qin[(size_t)row * HH + ln + 64] = q1v;
    }
    __syncthreads();

    int j = tid;   // 0..127: output column
    float aq[4] = {0,0,0,0}, ak[4] = {0,0,0,0}, av[4] = {0,0,0,0};
    for (int c = 0; c < 4; c++) {
        // stage Wq/Wk/Wv chunk [128 j][32 k], coalesced reads
        #pragma unroll
        for (int m = 0; m < 3; m++) {
            const float* Wm = (m == 0) ? Wq : (m == 1) ? Wk : Wv;
            #pragma unroll
            for (int p = 0; p < 8; p++) {
                int idx = tid + p * 128;
                int jj = idx >> 3, k4 = idx & 7;
                float4 w = *(const float4*)(Wm + (size_t)jj * HH + c * 32 + k4 * 4);
                float* dst = &Wst[m * HH * 33 + jj * 33 + k4 * 4];
                dst[0] = w.x; dst[1] = w.y; dst[2] = w.z; dst[3] = w.w;
            }
        }
        __syncthreads();
        #pragma unroll 4
        for (int kk = 0; kk < 32; kk++) {
            int k = c * 32 + kk;
            float4 xq4 = *(const float4*)&xT[k][0];
            float4 xs4 = *(const float4*)&xT[k][4];
            float wq = Wst[0 * HH * 33 + j * 33 + kk];
            float wk = Wst[1 * HH * 33 + j * 33 + kk];
            float wvv = Wst[2 * HH * 33 + j * 33 + kk];
            aq[0] += xq4.x * wq; aq[1] += xq4.y * wq; aq[2] += xq4.z * wq; aq[3] += xq4.w * wq;
            ak[0] += xs4.x * wk; ak[1] += xs4.y * wk; ak[2] += xs4.z * wk; ak[3] += xs4.w * wk;
            av[0] += xs4.x * wvv; av[1] += xs4.y * wvv; av[2] += xs4.z * wvv; av[3] += xs4.w * wvv;
        }
        __syncthreads();
    }
    float bqv = bq[j], bkv = bk[j], bvv = bv[j];
    #pragma unroll
    for (int r = 0; r < 4; r++) {
        int row = row0 + r;
        int l = row % LL;
        Q[(size_t)row * HH + j] = (aq[r] + bqv) * INV_SCALE;
        K[(size_t)row * HH + j] = ak[r] + bkv + posK[l * HH + j];
        V[(size_t)row * HH + j] = av[r] + bvv + posV[l * HH + j];
    }
}

// ===== tiled attention: block = (b, head, 8-q tile), 256 threads ==========
__global__ void k_attn(const float* __restrict__ Q, const float* __restrict__ K,
                       const float* __restrict__ V,
                       const float* __restrict__ timeK, const float* __restrict__ timeV,
                       const int* __restrict__ tm,
                       float* __restrict__ att) {
    int bn = blockIdx.x & 31;
    int b = bn >> 2, n = bn & 3;
    int qt = (NQT - 1) - (blockIdx.x >> 5);   // heavy tiles dispatch first
    int q0 = qt * QT;
    int kmax = q0 + QT - 1;
    int tid = threadIdx.x;
    int wv = tid >> 6, ln = tid & 63;

    __shared__ float Qs[QT * HDIM];       // 1 KB
    __shared__ float KstT[HDIM * KTP];    // 8.25 KB (transposed staging)
    __shared__ float DTW[QT * NT];        // 8.2 KB (DT table, then W bins)
    __shared__ float Ssc[QT * SSP];       // 6.5 KB (scores -> P)
    __shared__ int   tmst[QT * LL];       // 6.4 KB
    __shared__ float Ost[QT * HDIM];      // 1 KB

    // ---- A: Q tile, tm tile, zero Ost ----
    Ost[tid] = 0.f;                       // 256 == QT*HDIM
    if (tid < 64) {
        int qi = tid >> 3, d4 = tid & 7;
        *(float4*)(Qs + qi * HDIM + d4 * 4) =
            *(const float4*)(Q + ((size_t)(b * LL + q0 + qi)) * HH + n * HDIM + d4 * 4);
    }
    #pragma unroll
    for (int qi = 0; qi < QT; qi++)
        if (tid < LL)
            tmst[qi * LL + tid] = tm[((size_t)(b * LL + q0 + qi)) * LL + tid];
    __syncthreads();

    int k2 = tid & 31, qi_c = tid >> 5;

    // ---- B: DT[qi][tau] = Qh . timeKh[tau] ----
    for (int c = 0; c < 5; c++) {
        #pragma unroll
        for (int p = 0; p < 2; p++) {
            int idx = tid + p * 256;
            int r = idx >> 3, d4 = idx & 7;
            int tau = c * 64 + r;
            float4 w = make_float4(0.f, 0.f, 0.f, 0.f);
            if (tau < NT) w = *(const float4*)(timeK + (size_t)tau * HH + n * HDIM + d4 * 4);
            KstT[(d4 * 4 + 0) * KTP + r] = w.x;
            KstT[(d4 * 4 + 1) * KTP + r] = w.y;
            KstT[(d4 * 4 + 2) * KTP + r] = w.z;
            KstT[(d4 * 4 + 3) * KTP + r] = w.w;
        }
        __syncthreads();
        float a0 = 0.f, a1 = 0.f;
        #pragma unroll 4
        for (int d = 0; d < HDIM; d++) {
            float qv = Qs[qi_c * HDIM + d];
            float2 kv = *(const float2*)&KstT[d * KTP + k2 * 2];
            a0 += qv * kv.x; a1 += qv * kv.y;
        }
        int tau0 = c * 64 + k2 * 2;
        if (tau0 < NT)     DTW[qi_c * NT + tau0]     = a0;
        if (tau0 + 1 < NT) DTW[qi_c * NT + tau0 + 1] = a1;
        __syncthreads();
    }

    // ---- C: S[qi][k] = Qh.Kh[k] + DT[qi][tm[k]], causal-masked ----
    int nch = (kmax >> 6) + 1;
    for (int c = 0; c < nch; c++) {
        #pragma unroll
        for (int p = 0; p < 2; p++) {
            int idx = tid + p * 256;
            int r = idx >> 3, d4 = idx & 7;
            int k = c * 64 + r;
            float4 w = make_float4(0.f, 0.f, 0.f, 0.f);
            if (k < LL) w = *(const float4*)(K + ((size_t)(b * LL + k)) * HH + n * HDIM + d4 * 4);
            KstT[(d4 * 4 + 0) * KTP + r] = w.x;
            KstT[(d4 * 4 + 1) * KTP + r] = w.y;
            KstT[(d4 * 4 + 2) * KTP + r] = w.z;
            KstT[(d4 * 4 + 3) * KTP + r] = w.w;
        }
        __syncthreads();
        float a0 = 0.f, a1 = 0.f;
        #pragma unroll 4
        for (int d = 0; d < HDIM; d++) {
            float qv = Qs[qi_c * HDIM + d];
            float2 kv = *(const float2*)&KstT[d * KTP + k2 * 2];
            a0 += qv * kv.x; a1 += qv * kv.y;
        }
        int q = q0 + qi_c;
        int k0 = c * 64 + k2 * 2;
        if (k0 <= kmax)
            Ssc[qi_c * SSP + k0] = (k0 <= q) ? (a0 + DTW[qi_c * NT + tmst[qi_c * LL + k0]]) : PADV;
        if (k0 + 1 <= kmax)
            Ssc[qi_c * SSP + k0 + 1] = (k0 + 1 <= q) ? (a1 + DTW[qi_c * NT + tmst[qi_c * LL + k0 + 1]]) : PADV;
        __syncthreads();
    }

    // ---- zero DTW (reused as scatter bins W) ----
    for (int idx = tid; idx < QT * NT; idx += 256) DTW[idx] = 0.f;
    __syncthreads();

    // ---- D: softmax per q-row + scatter W; wave wv -> rows wv, wv+4 ----
    for (int rr = 0; rr < 2; rr++) {
        int qi = wv + rr * 4;
        int q = q0 + qi;
        float sv[4];
        float m = PADV;
        #pragma unroll
        for (int jj = 0; jj < 4; jj++) {
            int k = ln + 64 * jj;
            sv[jj] = (k <= q) ? Ssc[qi * SSP + k] : PADV;
            m = fmaxf(m, sv[jj]);
        }
        for (int off = 32; off; off >>= 1) m = fmaxf(m, __shfl_xor(m, off));
        float sum = 0.f;
        #pragma unroll
        for (int jj = 0; jj < 4; jj++) {
            int k = ln + 64 * jj;
            sv[jj] = (k <= q) ? __expf(sv[jj] - m) : 0.f;
            sum += sv[jj];
        }
        for (int off = 32; off; off >>= 1) sum += __shfl_xor(sum, off);
        float inv = 1.f / sum;
        #pragma unroll
        for (int jj = 0; jj < 4; jj++) {
            int k = ln + 64 * jj;
            float p = sv[jj] * inv;
            if (k < SSP) Ssc[qi * SSP + k] = (k <= q) ? p : 0.f;
            if (k <= q) atomicAdd(&DTW[qi * NT + tmst[qi * LL + k]], p);
        }
    }
    __syncthreads();

    // ---- E: O = P@Vh + W@timeVh, parallel over k-groups ----
    int d = tid & 31, kg = tid >> 5;
    float acc[QT] = {0,0,0,0,0,0,0,0};
    const float* vb = V + ((size_t)(b * LL)) * HH + n * HDIM + d;
    for (int k = kg; k <= kmax; k += 8) {
        float v = vb[(size_t)k * HH];
        #pragma unroll
        for (int qi = 0; qi < QT; qi++) acc[qi] += Ssc[qi * SSP + k] * v;
    }
    const float* tvb = timeV + n * HDIM + d;
    for (int t = kg; t < NT; t += 8) {
        float v = tvb[(size_t)t * HH];
        #pragma unroll
        for (int qi = 0; qi < QT; qi++) acc[qi] += DTW[qi * NT + t] * v;
    }
    #pragma unroll
    for (int qi = 0; qi < QT; qi++) atomicAdd(&Ost[qi * HDIM + d], acc[qi]);
    __syncthreads();
    {
        int qi = tid >> 5;
        att[((size_t)(b * LL + q0 + qi)) * HH + n * HDIM + d] = Ost[qi * HDIM + d];
    }
}

// ===== fused LN + FF1 + FF2 + keep: 4 rows/block, 128 threads =============
__global__ void k_lnffn(const float* __restrict__ Qin, const float* __restrict__ att,
                        const float* __restrict__ g, const float* __restrict__ bia,
                        const float* __restrict__ W1, const float* __restrict__ b1,
                        const float* __restrict__ W2, const float* __restrict__ b2,
                        const int* __restrict__ log_seqs, float* __restrict__ out) {
    int row0 = blockIdx.x * 4;
    int tid = threadIdx.x;
    int wv = tid >> 6, ln = tid & 63;
    __shared__ float xT[HH][8];        // cols 0-3: y rows, 4-7: h1 rows
    __shared__ float Wst[HH * 33];

    for (int rr = 0; rr < 2; rr++) {
        int r = 2 * wv + rr;
        int row = row0 + r;
        float v0 = Qin[(size_t)row * HH + ln]      + att[(size_t)row * HH + ln];
        float v1 = Qin[(size_t)row * HH + ln + 64] + att[(size_t)row * HH + ln + 64];
        float s = v0 + v1, s2 = v0 * v0 + v1 * v1;
        for (int off = 32; off; off >>= 1) {
            s  += __shfl_xor(s, off);
            s2 += __shfl_xor(s2, off);
        }
        float mean = s * (1.f / HH);
        float var  = s2 * (1.f / HH) - mean * mean;
        float inv  = 1.f / sqrtf(var + 1e-8f);
        xT[ln][r]      = (v0 - mean) * inv * g[ln]      + bia[ln];
        xT[ln + 64][r] = (v1 - mean) * inv * g[ln + 64] + bia[ln + 64];
    }
    __syncthreads();

    int j = tid;
    float a[4] = {0,0,0,0};
    for (int c = 0; c < 4; c++) {
        #pragma unroll
        for (int p = 0; p < 8; p++) {
            int idx = tid + p * 128;
            int jj = idx >> 3, k4 = idx & 7;
            float4 w = *(const float4*)(W1 + (size_t)jj * HH + c * 32 + k4 * 4);
            float* dst = &Wst[jj * 33 + k4 * 4];
            dst[0] = w.x; dst[1] = w.y; dst[2] = w.z; dst[3] = w.w;
        }
        __syncthreads();
        #pragma unroll 4
        for (int kk = 0; kk < 32; kk++) {
            int k = c * 32 + kk;
            float4 x4 = *(const float4*)&xT[k][0];
            float w = Wst[j * 33 + kk];
            a[0] += x4.x * w; a[1] += x4.y * w; a[2] += x4.z * w; a[3] += x4.w * w;
        }
        __syncthreads();
    }
    float b1v = b1[j];
    #pragma unroll
    for (int r = 0; r < 4; r++) {
        float t = a[r] + b1v;
        xT[j][4 + r] = t > 0.f ? t : 0.f;
    }
    __syncthreads();

    float c2[4] = {0,0,0,0};
    for (int c = 0; c < 4; c++) {
        #pragma unroll
        for (int p = 0; p < 8; p++) {
            int idx = tid + p * 128;
            int jj = idx >> 3, k4 = idx & 7;
            float4 w = *(const float4*)(W2 + (size_t)jj * HH + c * 32 + k4 * 4);
            float* dst = &Wst[jj * 33 + k4 * 4];
            dst[0] = w.x; dst[1] = w.y; dst[2] = w.z; dst[3] = w.w;
        }
        __syncthreads();
        #pragma unroll 4
        for (int kk = 0; kk < 32; kk++) {
            int k = c * 32 + kk;
            float4 x4 = *(const float4*)&xT[k][4];
            float w = Wst[j * 33 + kk];
            c2[0] += x4.x * w; c2[1] += x4.y * w; c2[2] += x4.z * w; c2[3] += x4.w * w;
        }
        __syncthreads();
    }
    float b2v = b2[j];
    float4 y4 = *(const float4*)&xT[j][0];
    float yv[4] = {y4.x, y4.y, y4.z, y4.w};
    #pragma unroll
    for (int r = 0; r < 4; r++) {
        int row = row0 + r;
        float t = c2[r] + b2v + yv[r];
        out[(size_t)row * HH + j] = (log_seqs[row] == 0) ? 0.f : t;
    }
}

// ===== fused last-LN + pos/neg logits: one block per row ==================
__global__ void k_lnlogits(const float* __restrict__ seqs,
                           const float* __restrict__ g, const float* __restrict__ bia,
                           const float* __restrict__ item_emb,
                           const int* __restrict__ pos, const int* __restrict__ neg,
                           float* __restrict__ out) {
    int row = blockIdx.x;
    int h = threadIdx.x;
    float v = seqs[(size_t)row * HH + h];
    float s = v, s2 = v * v;
    for (int off = 32; off; off >>= 1) {
        s  += __shfl_xor(s, off);
        s2 += __shfl_xor(s2, off);
    }
    __shared__ float r1[2], r2[2];
    if ((h & 63) == 0) { r1[h >> 6] = s; r2[h >> 6] = s2; }
    __syncthreads();
    float mean = (r1[0] + r1[1]) * (1.f / HH);
    float var  = (r2[0] + r2[1]) * (1.f / HH) - mean * mean;
    float inv = 1.f / sqrtf(var + 1e-8f);
    float f = (v - mean) * inv * g[h] + bia[h];

    int ip = pos[row], in_ = neg[row];
    float vp = f * item_emb[(size_t)ip * HH + h];
    float vn = f * item_emb[(size_t)in_ * HH + h];
    for (int off = 32; off; off >>= 1) {
        vp += __shfl_xor(vp, off);
        vn += __shfl_xor(vn, off);
    }
    __shared__ float rp[2], rn[2];
    if ((h & 63) == 0) { rp[h >> 6] = vp; rn[h >> 6] = vn; }
    __syncthreads();
    if (h == 0) {
        out[row]      = rp[0] + rp[1];
        out[BL + row] = rn[0] + rn[1];
    }
}

extern "C" void kernel_launch(void* const* d_in, const int* in_sizes, int n_in,
                              void* d_out, int out_size, void* d_ws, size_t ws_size,
                              hipStream_t stream) {
    const int* log_seqs   = (const int*)d_in[1];
    const int* tm         = (const int*)d_in[2];
    const int* pos_seqs   = (const int*)d_in[3];
    const int* neg_seqs   = (const int*)d_in[4];
    const float* item_emb = (const float*)d_in[5];
    const float* posK     = (const float*)d_in[6];
    const float* posV     = (const float*)d_in[7];
    const float* timeK    = (const float*)d_in[8];
    const float* timeV    = (const float*)d_in[9];
    const float* attn_g   = (const float*)d_in[10];
    const float* attn_b   = (const float*)d_in[11];
    const float* Wq       = (const float*)d_in[12];
    const float* bq       = (const float*)d_in[13];
    const float* Wk       = (const float*)d_in[14];
    const float* bk       = (const float*)d_in[15];
    const float* Wv       = (const float*)d_in[16];
    const float* bv       = (const float*)d_in[17];
    const float* fwd_g    = (const float*)d_in[18];
    const float* fwd_b    = (const float*)d_in[19];
    const float* W1       = (const float*)d_in[20];
    const float* b1       = (const float*)d_in[21];
    const float* W2       = (const float*)d_in[22];
    const float* b2       = (const float*)d_in[23];
    const float* last_g   = (const float*)d_in[24];
    const float* last_b   = (const float*)d_in[25];

    float* seqs = (float*)d_ws;            // 6 x B*L*H f32 = ~4.9 MB
    float* Qin  = seqs + (size_t)BL * HH;
    float* Qb   = Qin  + (size_t)BL * HH;
    float* Kb   = Qb   + (size_t)BL * HH;
    float* Vb   = Kb   + (size_t)BL * HH;
    float* att  = Vb   + (size_t)BL * HH;

    for (int i = 0; i < NBLK; i++) {
        k_lnqkv<<<BL / 4, 128, 0, stream>>>(i == 0 ? nullptr : seqs, log_seqs, item_emb,
                                            attn_g + i * HH, attn_b + i * HH,
                                            Wq + (size_t)i * HH * HH, bq + i * HH,
                                            Wk + (size_t)i * HH * HH, bk + i * HH,
                                            Wv + (size_t)i * HH * HH, bv + i * HH,
                                            posK, posV, Qin, Qb, Kb, Vb);
        k_attn<<<NQT * 32, 256, 0, stream>>>(Qb, Kb, Vb, timeK, timeV, tm, att);
        k_lnffn<<<BL / 4, 128, 0, stream>>>(Qin, att, fwd_g + i * HH, fwd_b + i * HH,
                                            W1 + (size_t)i * HH * HH, b1 + i * HH,
                                            W2 + (size_t)i * HH * HH, b2 + i * HH,
                                            log_seqs, seqs);
    }
    k_lnlogits<<<BL, HH, 0, stream>>>(seqs, last_g, last_b, item_emb,
                                      pos_seqs, neg_seqs, (float*)d_out);
}

// Round 7
// 241.028 us; speedup vs baseline: 1.3096x; 1.1199x over previous
//
#include <hip/hip_runtime.h>
#include <hip/hip_bf16.h>

#define BB 8
#define LL 200
#define HH 128
#define NHEAD 4
#define HDIM 32
#define NBLK 2
#define BL (BB * LL)
#define NT 257            // TIME_SPAN+1
#define QT 8              // queries per attention tile
#define NQT 25            // 200/8
#define SSP 208           // attn score row stride
#define KTP 66            // attn KstT row stride
#define ASP 36            // qkv A-tile stride [k][m], m<32 (16B-aligned)
#define BSP 66            // B-tile stride [k][j], j<64 (8B-aligned)
#define FASP 20           // ff A-tile stride [k][m], m<16
#define RSP 132           // ff2 residual tile stride [r][k]

static constexpr float SQRT_H    = 11.313708498984761f;   // sqrt(128)
static constexpr float INV_SCALE = 0.17677669529663687f;  // 1/sqrt(32)
static constexpr float PADV      = -4294967295.0f;        // -2^32+1

// ===== QKV GEMM: [1600x128] @ [128x384], 50 Mtiles x 6 Ntiles ==============
// N-tiles 0,1 -> Q (A = LN(x)); 2,3 -> K (+posK); 4,5 -> V (+posV)
// layer 0: x = embed gather; Qin written by nt==0 blocks.
__global__ void k_qkv_gemm(const float* __restrict__ seqs_in,
                           const int* __restrict__ log_seqs,
                           const float* __restrict__ item_emb,
                           const float* __restrict__ g, const float* __restrict__ bia,
                           const float* __restrict__ Wq, const float* __restrict__ bq,
                           const float* __restrict__ Wk, const float* __restrict__ bk,
                           const float* __restrict__ Wv, const float* __restrict__ bv,
                           const float* __restrict__ posK, const float* __restrict__ posV,
                           float* __restrict__ Qin, float* __restrict__ Q,
                           float* __restrict__ K, float* __restrict__ V) {
    int mt = blockIdx.x / 6, nt = blockIdx.x % 6;
    int matsel = nt >> 1;              // 0=Q 1=K 2=V
    int jb = (nt & 1) * 64;
    int row0 = mt * 32;
    int tid = threadIdx.x;
    __shared__ float As[128 * ASP];    // 18.4 KB, [k][m]
    __shared__ float Bs[128 * BSP];    // 33.8 KB, [k][j]

    // ---- stage A: 32 rows x 128, 8 threads/row; LN for Q-tiles ----
    {
        int r = tid >> 3, seg = tid & 7;
        int row = row0 + r;
        float4 vv[4];
        if (seqs_in) {
            #pragma unroll
            for (int i = 0; i < 4; i++)
                vv[i] = *(const float4*)(seqs_in + (size_t)row * HH + seg * 16 + i * 4);
        } else {
            int idx = log_seqs[row];
            if (idx == 0) {
                #pragma unroll
                for (int i = 0; i < 4; i++) vv[i] = make_float4(0.f, 0.f, 0.f, 0.f);
            } else {
                #pragma unroll
                for (int i = 0; i < 4; i++) {
                    float4 e = *(const float4*)(item_emb + (size_t)idx * HH + seg * 16 + i * 4);
                    vv[i] = make_float4(e.x * SQRT_H, e.y * SQRT_H, e.z * SQRT_H, e.w * SQRT_H);
                }
            }
        }
        if (matsel == 0) {
            float s = 0.f, s2 = 0.f;
            #pragma unroll
            for (int i = 0; i < 4; i++) {
                s  += vv[i].x + vv[i].y + vv[i].z + vv[i].w;
                s2 += vv[i].x * vv[i].x + vv[i].y * vv[i].y + vv[i].z * vv[i].z + vv[i].w * vv[i].w;
            }
            #pragma unroll
            for (int off = 1; off < 8; off <<= 1) {
                s  += __shfl_xor(s, off);
                s2 += __shfl_xor(s2, off);
            }
            float mean = s * (1.f / HH);
            float var  = s2 * (1.f / HH) - mean * mean;
            float inv  = 1.f / sqrtf(var + 1e-8f);
            #pragma unroll
            for (int i = 0; i < 4; i++) {
                int k = seg * 16 + i * 4;
                float4 g4 = *(const float4*)(g + k);
                float4 b4 = *(const float4*)(bia + k);
                float4 y;
                y.x = (vv[i].x - mean) * inv * g4.x + b4.x;
                y.y = (vv[i].y - mean) * inv * g4.y + b4.y;
                y.z = (vv[i].z - mean) * inv * g4.z + b4.z;
                y.w = (vv[i].w - mean) * inv * g4.w + b4.w;
                As[(k + 0) * ASP + r] = y.x;
                As[(k + 1) * ASP + r] = y.y;
                As[(k + 2) * ASP + r] = y.z;
                As[(k + 3) * ASP + r] = y.w;
                if (nt == 0) *(float4*)(Qin + (size_t)row * HH + k) = y;
            }
        } else {
            #pragma unroll
            for (int i = 0; i < 4; i++) {
                int k = seg * 16 + i * 4;
                As[(k + 0) * ASP + r] = vv[i].x;
                As[(k + 1) * ASP + r] = vv[i].y;
                As[(k + 2) * ASP + r] = vv[i].z;
                As[(k + 3) * ASP + r] = vv[i].w;
            }
        }
    }
    // ---- stage B: 64 W-rows x 128 k, coalesced full-row reads ----
    {
        const float* W = (matsel == 0) ? Wq : (matsel == 1) ? Wk : Wv;
        int k4 = tid & 31, jj0 = tid >> 5;
        #pragma unroll
        for (int p = 0; p < 8; p++) {
            int jj = jj0 + p * 8;
            float4 w = *(const float4*)(W + (size_t)(jb + jj) * HH + k4 * 4);
            Bs[(k4 * 4 + 0) * BSP + jj] = w.x;
            Bs[(k4 * 4 + 1) * BSP + jj] = w.y;
            Bs[(k4 * 4 + 2) * BSP + jj] = w.z;
            Bs[(k4 * 4 + 3) * BSP + jj] = w.w;
        }
    }
    __syncthreads();

    // ---- K loop: thread = (my: 4 rows, jx: 2 cols) ----
    int my = tid >> 5, jx = tid & 31;
    float a00=0,a01=0,a10=0,a11=0,a20=0,a21=0,a30=0,a31=0;
    #pragma unroll 4
    for (int k = 0; k < HH; k++) {
        float4 a = *(const float4*)&As[k * ASP + my * 4];
        float2 b = *(const float2*)&Bs[k * BSP + jx * 2];
        a00 += a.x * b.x; a01 += a.x * b.y;
        a10 += a.y * b.x; a11 += a.y * b.y;
        a20 += a.z * b.x; a21 += a.z * b.y;
        a30 += a.w * b.x; a31 += a.w * b.y;
    }
    float accs[4][2] = {{a00,a01},{a10,a11},{a20,a21},{a30,a31}};
    int col = jb + jx * 2;
    if (matsel == 0) {
        float2 bb = *(const float2*)(bq + col);
        #pragma unroll
        for (int r = 0; r < 4; r++) {
            int row = row0 + my * 4 + r;
            float2 o = make_float2((accs[r][0] + bb.x) * INV_SCALE,
                                   (accs[r][1] + bb.y) * INV_SCALE);
            *(float2*)(Q + (size_t)row * HH + col) = o;
        }
    } else if (matsel == 1) {
        float2 bb = *(const float2*)(bk + col);
        #pragma unroll
        for (int r = 0; r < 4; r++) {
            int row = row0 + my * 4 + r;
            int l = row % LL;
            float2 pk = *(const float2*)(posK + (size_t)l * HH + col);
            float2 o = make_float2(accs[r][0] + bb.x + pk.x, accs[r][1] + bb.y + pk.y);
            *(float2*)(K + (size_t)row * HH + col) = o;
        }
    } else {
        float2 bb = *(const float2*)(bv + col);
        #pragma unroll
        for (int r = 0; r < 4; r++) {
            int row = row0 + my * 4 + r;
            int l = row % LL;
            float2 pv = *(const float2*)(posV + (size_t)l * HH + col);
            float2 o = make_float2(accs[r][0] + bb.x + pv.x, accs[r][1] + bb.y + pv.y);
            *(float2*)(V + (size_t)row * HH + col) = o;
        }
    }
}

// ===== tiled attention: block = (b, head, 8-q tile), 256 threads ==========
__global__ void k_attn(const float* __restrict__ Q, const float* __restrict__ K,
                       const float* __restrict__ V,
                       const float* __restrict__ timeK, const float* __restrict__ timeV,
                       const int* __restrict__ tm,
                       float* __restrict__ att) {
    int bn = blockIdx.x & 31;
    int b = bn >> 2, n = bn & 3;
    int qt = (NQT - 1) - (blockIdx.x >> 5);   // heavy tiles dispatch first
    int q0 = qt * QT;
    int kmax = q0 + QT - 1;
    int tid = threadIdx.x;
    int wv = tid >> 6, ln = tid & 63;

    __shared__ float Qs[QT * HDIM];
    __shared__ float KstT[HDIM * KTP];
    __shared__ float DTW[QT * NT];
    __shared__ float Ssc[QT * SSP];
    __shared__ int   tmst[QT * LL];
    __shared__ float Ost[QT * HDIM];

    Ost[tid] = 0.f;
    if (tid < 64) {
        int qi = tid >> 3, d4 = tid & 7;
        *(float4*)(Qs + qi * HDIM + d4 * 4) =
            *(const float4*)(Q + ((size_t)(b * LL + q0 + qi)) * HH + n * HDIM + d4 * 4);
    }
    #pragma unroll
    for (int qi = 0; qi < QT; qi++)
        if (tid < LL)
            tmst[qi * LL + tid] = tm[((size_t)(b * LL + q0 + qi)) * LL + tid];
    __syncthreads();

    int k2 = tid & 31, qi_c = tid >> 5;

    // DT[qi][tau] = Qh . timeKh[tau]
    for (int c = 0; c < 5; c++) {
        #pragma unroll
        for (int p = 0; p < 2; p++) {
            int idx = tid + p * 256;
            int r = idx >> 3, d4 = idx & 7;
            int tau = c * 64 + r;
            float4 w = make_float4(0.f, 0.f, 0.f, 0.f);
            if (tau < NT) w = *(const float4*)(timeK + (size_t)tau * HH + n * HDIM + d4 * 4);
            KstT[(d4 * 4 + 0) * KTP + r] = w.x;
            KstT[(d4 * 4 + 1) * KTP + r] = w.y;
            KstT[(d4 * 4 + 2) * KTP + r] = w.z;
            KstT[(d4 * 4 + 3) * KTP + r] = w.w;
        }
        __syncthreads();
        float a0 = 0.f, a1 = 0.f;
        #pragma unroll 4
        for (int d = 0; d < HDIM; d++) {
            float qv = Qs[qi_c * HDIM + d];
            float2 kv = *(const float2*)&KstT[d * KTP + k2 * 2];
            a0 += qv * kv.x; a1 += qv * kv.y;
        }
        int tau0 = c * 64 + k2 * 2;
        if (tau0 < NT)     DTW[qi_c * NT + tau0]     = a0;
        if (tau0 + 1 < NT) DTW[qi_c * NT + tau0 + 1] = a1;
        __syncthreads();
    }

    // S[qi][k] = Qh.Kh[k] + DT[qi][tm[k]], causal
    int nch = (kmax >> 6) + 1;
    for (int c = 0; c < nch; c++) {
        #pragma unroll
        for (int p = 0; p < 2; p++) {
            int idx = tid + p * 256;
            int r = idx >> 3, d4 = idx & 7;
            int k = c * 64 + r;
            float4 w = make_float4(0.f, 0.f, 0.f, 0.f);
            if (k < LL) w = *(const float4*)(K + ((size_t)(b * LL + k)) * HH + n * HDIM + d4 * 4);
            KstT[(d4 * 4 + 0) * KTP + r] = w.x;
            KstT[(d4 * 4 + 1) * KTP + r] = w.y;
            KstT[(d4 * 4 + 2) * KTP + r] = w.z;
            KstT[(d4 * 4 + 3) * KTP + r] = w.w;
        }
        __syncthreads();
        float a0 = 0.f, a1 = 0.f;
        #pragma unroll 4
        for (int d = 0; d < HDIM; d++) {
            float qv = Qs[qi_c * HDIM + d];
            float2 kv = *(const float2*)&KstT[d * KTP + k2 * 2];
            a0 += qv * kv.x; a1 += qv * kv.y;
        }
        int q = q0 + qi_c;
        int k0 = c * 64 + k2 * 2;
        if (k0 <= kmax)
            Ssc[qi_c * SSP + k0] = (k0 <= q) ? (a0 + DTW[qi_c * NT + tmst[qi_c * LL + k0]]) : PADV;
        if (k0 + 1 <= kmax)
            Ssc[qi_c * SSP + k0 + 1] = (k0 + 1 <= q) ? (a1 + DTW[qi_c * NT + tmst[qi_c * LL + k0 + 1]]) : PADV;
        __syncthreads();
    }

    for (int idx = tid; idx < QT * NT; idx += 256) DTW[idx] = 0.f;
    __syncthreads();

    // softmax + scatter W
    for (int rr = 0; rr < 2; rr++) {
        int qi = wv + rr * 4;
        int q = q0 + qi;
        float sv[4];
        float m = PADV;
        #pragma unroll
        for (int jj = 0; jj < 4; jj++) {
            int k = ln + 64 * jj;
            sv[jj] = (k <= q) ? Ssc[qi * SSP + k] : PADV;
            m = fmaxf(m, sv[jj]);
        }
        for (int off = 32; off; off >>= 1) m = fmaxf(m, __shfl_xor(m, off));
        float sum = 0.f;
        #pragma unroll
        for (int jj = 0; jj < 4; jj++) {
            int k = ln + 64 * jj;
            sv[jj] = (k <= q) ? __expf(sv[jj] - m) : 0.f;
            sum += sv[jj];
        }
        for (int off = 32; off; off >>= 1) sum += __shfl_xor(sum, off);
        float inv = 1.f / sum;
        #pragma unroll
        for (int jj = 0; jj < 4; jj++) {
            int k = ln + 64 * jj;
            float p = sv[jj] * inv;
            if (k < SSP) Ssc[qi * SSP + k] = (k <= q) ? p : 0.f;
            if (k <= q) atomicAdd(&DTW[qi * NT + tmst[qi * LL + k]], p);
        }
    }
    __syncthreads();

    // O = P@Vh + W@timeVh
    int d = tid & 31, kg = tid >> 5;
    float acc[QT] = {0,0,0,0,0,0,0,0};
    const float* vb = V + ((size_t)(b * LL)) * HH + n * HDIM + d;
    for (int k = kg; k <= kmax; k += 8) {
        float v = vb[(size_t)k * HH];
        #pragma unroll
        for (int qi = 0; qi < QT; qi++) acc[qi] += Ssc[qi * SSP + k] * v;
    }
    const float* tvb = timeV + n * HDIM + d;
    for (int t = kg; t < NT; t += 8) {
        float v = tvb[(size_t)t * HH];
        #pragma unroll
        for (int qi = 0; qi < QT; qi++) acc[qi] += DTW[qi * NT + t] * v;
    }
    #pragma unroll
    for (int qi = 0; qi < QT; qi++) atomicAdd(&Ost[qi * HDIM + d], acc[qi]);
    __syncthreads();
    {
        int qi = tid >> 5;
        att[((size_t)(b * LL + q0 + qi)) * HH + n * HDIM + d] = Ost[qi * HDIM + d];
    }
}

// ===== FF1 GEMM: h1 = relu(LN(Qin+att)@W1^T + b1), M=16 N=64 ==============
__global__ void k_ff1(const float* __restrict__ Qin, const float* __restrict__ att,
                      const float* __restrict__ g, const float* __restrict__ bia,
                      const float* __restrict__ W1, const float* __restrict__ b1,
                      float* __restrict__ h1) {
    int mt = blockIdx.x >> 1, nt = blockIdx.x & 1;
    int jb = nt * 64;
    int row0 = mt * 16;
    int tid = threadIdx.x;
    __shared__ float As[128 * FASP];
    __shared__ float Bs[128 * BSP];

    {   // stage A = LN(Qin+att): 16 threads/row
        int r = tid >> 4, seg = tid & 15;
        int row = row0 + r;
        float4 vv[2];
        #pragma unroll
        for (int i = 0; i < 2; i++) {
            int k = seg * 8 + i * 4;
            float4 q4 = *(const float4*)(Qin + (size_t)row * HH + k);
            float4 a4 = *(const float4*)(att + (size_t)row * HH + k);
            vv[i] = make_float4(q4.x + a4.x, q4.y + a4.y, q4.z + a4.z, q4.w + a4.w);
        }
        float s = 0.f, s2 = 0.f;
        #pragma unroll
        for (int i = 0; i < 2; i++) {
            s  += vv[i].x + vv[i].y + vv[i].z + vv[i].w;
            s2 += vv[i].x * vv[i].x + vv[i].y * vv[i].y + vv[i].z * vv[i].z + vv[i].w * vv[i].w;
        }
        #pragma unroll
        for (int off = 1; off < 16; off <<= 1) {
            s  += __shfl_xor(s, off);
            s2 += __shfl_xor(s2, off);
        }
        float mean = s * (1.f / HH);
        float var  = s2 * (1.f / HH) - mean * mean;
        float inv  = 1.f / sqrtf(var + 1e-8f);
        #pragma unroll
        for (int i = 0; i < 2; i++) {
            int k = seg * 8 + i * 4;
            float4 g4 = *(const float4*)(g + k);
            float4 b4 = *(const float4*)(bia + k);
            As[(k + 0) * FASP + r] = (vv[i].x - mean) * inv * g4.x + b4.x;
            As[(k + 1) * FASP + r] = (vv[i].y - mean) * inv * g4.y + b4.y;
            As[(k + 2) * FASP + r] = (vv[i].z - mean) * inv * g4.z + b4.z;
            As[(k + 3) * FASP + r] = (vv[i].w - mean) * inv * g4.w + b4.w;
        }
    }
    {   // stage B from W1
        int k4 = tid & 31, jj0 = tid >> 5;
        #pragma unroll
        for (int p = 0; p < 8; p++) {
            int jj = jj0 + p * 8;
            float4 w = *(const float4*)(W1 + (size_t)(jb + jj) * HH + k4 * 4);
            Bs[(k4 * 4 + 0) * BSP + jj] = w.x;
            Bs[(k4 * 4 + 1) * BSP + jj] = w.y;
            Bs[(k4 * 4 + 2) * BSP + jj] = w.z;
            Bs[(k4 * 4 + 3) * BSP + jj] = w.w;
        }
    }
    __syncthreads();

    int my = tid >> 5, jx = tid & 31;
    float a00 = 0, a01 = 0, a10 = 0, a11 = 0;
    #pragma unroll 4
    for (int k = 0; k < HH; k++) {
        float2 a = *(const float2*)&As[k * FASP + my * 2];
        float2 b = *(const float2*)&Bs[k * BSP + jx * 2];
        a00 += a.x * b.x; a01 += a.x * b.y;
        a10 += a.y * b.x; a11 += a.y * b.y;
    }
    int col = jb + jx * 2;
    float2 bb = *(const float2*)(b1 + col);
    {
        int row = row0 + my * 2;
        float2 o0 = make_float2(fmaxf(a00 + bb.x, 0.f), fmaxf(a01 + bb.y, 0.f));
        float2 o1 = make_float2(fmaxf(a10 + bb.x, 0.f), fmaxf(a11 + bb.y, 0.f));
        *(float2*)(h1 + (size_t)row * HH + col) = o0;
        *(float2*)(h1 + (size_t)(row + 1) * HH + col) = o1;
    }
}

// ===== FF2 GEMM: out = (h1@W2^T + b2 + LN(Qin+att)) * keep, M=16 N=64 =====
__global__ void k_ff2(const float* __restrict__ h1,
                      const float* __restrict__ Qin, const float* __restrict__ att,
                      const float* __restrict__ g, const float* __restrict__ bia,
                      const float* __restrict__ W2, const float* __restrict__ b2,
                      const int* __restrict__ log_seqs,
                      float* __restrict__ out) {
    int mt = blockIdx.x >> 1, nt = blockIdx.x & 1;
    int jb = nt * 64;
    int row0 = mt * 16;
    int tid = threadIdx.x;
    __shared__ float As[128 * FASP];
    __shared__ float Bs[128 * BSP];
    __shared__ float Rs[16 * RSP];
    __shared__ float mu[16], rstd[16];

    {   // stage A = h1 tile; stage R = Qin+att + row stats
        int r = tid >> 4, seg = tid & 15;
        int row = row0 + r;
        #pragma unroll
        for (int i = 0; i < 2; i++) {
            int k = seg * 8 + i * 4;
            float4 h4 = *(const float4*)(h1 + (size_t)row * HH + k);
            As[(k + 0) * FASP + r] = h4.x;
            As[(k + 1) * FASP + r] = h4.y;
            As[(k + 2) * FASP + r] = h4.z;
            As[(k + 3) * FASP + r] = h4.w;
        }
        float s = 0.f, s2 = 0.f;
        #pragma unroll
        for (int i = 0; i < 2; i++) {
            int k = seg * 8 + i * 4;
            float4 q4 = *(const float4*)(Qin + (size_t)row * HH + k);
            float4 a4 = *(const float4*)(att + (size_t)row * HH + k);
            float4 v = make_float4(q4.x + a4.x, q4.y + a4.y, q4.z + a4.z, q4.w + a4.w);
            *(float4*)(Rs + r * RSP + k) = v;
            s  += v.x + v.y + v.z + v.w;
            s2 += v.x * v.x + v.y * v.y + v.z * v.z + v.w * v.w;
        }
        #pragma unroll
        for (int off = 1; off < 16; off <<= 1) {
            s  += __shfl_xor(s, off);
            s2 += __shfl_xor(s2, off);
        }
        float mean = s * (1.f / HH);
        float var  = s2 * (1.f / HH) - mean * mean;
        if (seg == 0) { mu[r] = mean; rstd[r] = 1.f / sqrtf(var + 1e-8f); }
    }
    {   // stage B from W2
        int k4 = tid & 31, jj0 = tid >> 5;
        #pragma unroll
        for (int p = 0; p < 8; p++) {
            int jj = jj0 + p * 8;
            float4 w = *(const float4*)(W2 + (size_t)(jb + jj) * HH + k4 * 4);
            Bs[(k4 * 4 + 0) * BSP + jj] = w.x;
            Bs[(k4 * 4 + 1) * BSP + jj] = w.y;
            Bs[(k4 * 4 + 2) * BSP + jj] = w.z;
            Bs[(k4 * 4 + 3) * BSP + jj] = w.w;
        }
    }
    __syncthreads();

    int my = tid >> 5, jx = tid & 31;
    float a00 = 0, a01 = 0, a10 = 0, a11 = 0;
    #pragma unroll 4
    for (int k = 0; k < HH; k++) {
        float2 a = *(const float2*)&As[k * FASP + my * 2];
        float2 b = *(const float2*)&Bs[k * BSP + jx * 2];
        a00 += a.x * b.x; a01 += a.x * b.y;
        a10 += a.y * b.x; a11 += a.y * b.y;
    }
    int col = jb + jx * 2;
    float2 bb = *(const float2*)(b2 + col);
    float2 g2 = *(const float2*)(g + col);
    float2 lb = *(const float2*)(bia + col);
    float accs[2][2] = {{a00, a01}, {a10, a11}};
    #pragma unroll
    for (int r = 0; r < 2; r++) {
        int ri = my * 2 + r;
        int row = row0 + ri;
        float m = mu[ri], iv = rstd[ri];
        float2 R = *(const float2*)&Rs[ri * RSP + col];
        float y0 = (R.x - m) * iv * g2.x + lb.x;
        float y1 = (R.y - m) * iv * g2.y + lb.y;
        float2 o = make_float2(accs[r][0] + bb.x + y0, accs[r][1] + bb.y + y1);
        if (log_seqs[row] == 0) o = make_float2(0.f, 0.f);
        *(float2*)(out + (size_t)row * HH + col) = o;
    }
}

// ===== fused last-LN + pos/neg logits: one block per row ==================
__global__ void k_lnlogits(const float* __restrict__ seqs,
                           const float* __restrict__ g, const float* __restrict__ bia,
                           const float* __restrict__ item_emb,
                           const int* __restrict__ pos, const int* __restrict__ neg,
                           float* __restrict__ out) {
    int row = blockIdx.x;
    int h = threadIdx.x;
    float v = seqs[(size_t)row * HH + h];
    float s = v, s2 = v * v;
    for (int off = 32; off; off >>= 1) {
        s  += __shfl_xor(s, off);
        s2 += __shfl_xor(s2, off);
    }
    __shared__ float r1[2], r2[2];
    if ((h & 63) == 0) { r1[h >> 6] = s; r2[h >> 6] = s2; }
    __syncthreads();
    float mean = (r1[0] + r1[1]) * (1.f / HH);
    float var  = (r2[0] + r2[1]) * (1.f / HH) - mean * mean;
    float inv = 1.f / sqrtf(var + 1e-8f);
    float f = (v - mean) * inv * g[h] + bia[h];

    int ip = pos[row], in_ = neg[row];
    float vp = f * item_emb[(size_t)ip * HH + h];
    float vn = f * item_emb[(size_t)in_ * HH + h];
    for (int off = 32; off; off >>= 1) {
        vp += __shfl_xor(vp, off);
        vn += __shfl_xor(vn, off);
    }
    __shared__ float rp[2], rn[2];
    if ((h & 63) == 0) { rp[h >> 6] = vp; rn[h >> 6] = vn; }
    __syncthreads();
    if (h == 0) {
        out[row]      = rp[0] + rp[1];
        out[BL + row] = rn[0] + rn[1];
    }
}

extern "C" void kernel_launch(void* const* d_in, const int* in_sizes, int n_in,
                              void* d_out, int out_size, void* d_ws, size_t ws_size,
                              hipStream_t stream) {
    const int* log_seqs   = (const int*)d_in[1];
    const int* tm         = (const int*)d_in[2];
    const int* pos_seqs   = (const int*)d_in[3];
    const int* neg_seqs   = (const int*)d_in[4];
    const float* item_emb = (const float*)d_in[5];
    const float* posK     = (const float*)d_in[6];
    const float* posV     = (const float*)d_in[7];
    const float* timeK    = (const float*)d_in[8];
    const float* timeV    = (const float*)d_in[9];
    const float* attn_g   = (const float*)d_in[10];
    const float* attn_b   = (const float*)d_in[11];
    const float* Wq       = (const float*)d_in[12];
    const float* bq       = (const float*)d_in[13];
    const float* Wk       = (const float*)d_in[14];
    const float* bk       = (const float*)d_in[15];
    const float* Wv       = (const float*)d_in[16];
    const float* bv       = (const float*)d_in[17];
    const float* fwd_g    = (const float*)d_in[18];
    const float* fwd_b    = (const float*)d_in[19];
    const float* W1       = (const float*)d_in[20];
    const float* b1       = (const float*)d_in[21];
    const float* W2       = (const float*)d_in[22];
    const float* b2       = (const float*)d_in[23];
    const float* last_g   = (const float*)d_in[24];
    const float* last_b   = (const float*)d_in[25];

    float* seqs = (float*)d_ws;            // 7 x B*L*H f32 = ~5.7 MB
    float* Qin  = seqs + (size_t)BL * HH;
    float* Qb   = Qin  + (size_t)BL * HH;
    float* Kb   = Qb   + (size_t)BL * HH;
    float* Vb   = Kb   + (size_t)BL * HH;
    float* att  = Vb   + (size_t)BL * HH;
    float* h1   = att  + (size_t)BL * HH;

    for (int i = 0; i < NBLK; i++) {
        k_qkv_gemm<<<300, 256, 0, stream>>>(i == 0 ? nullptr : seqs, log_seqs, item_emb,
                                            attn_g + i * HH, attn_b + i * HH,
                                            Wq + (size_t)i * HH * HH, bq + i * HH,
                                            Wk + (size_t)i * HH * HH, bk + i * HH,
                                            Wv + (size_t)i * HH * HH, bv + i * HH,
                                            posK, posV, Qin, Qb, Kb, Vb);
        k_attn<<<NQT * 32, 256, 0, stream>>>(Qb, Kb, Vb, timeK, timeV, tm, att);
        k_ff1<<<200, 256, 0, stream>>>(Qin, att, fwd_g + i * HH, fwd_b + i * HH,
                                       W1 + (size_t)i * HH * HH, b1 + i * HH, h1);
        k_ff2<<<200, 256, 0, stream>>>(h1, Qin, att, fwd_g + i * HH, fwd_b + i * HH,
                                       W2 + (size_t)i * HH * HH, b2 + i * HH,
                                       log_seqs, seqs);
    }
    k_lnlogits<<<BL, HH, 0, stream>>>(seqs, last_g, last_b, item_emb,
                                      pos_seqs, neg_seqs, (float*)d_out);
}